// Round 11
// baseline (164.913 us; speedup 1.0000x reference)
//
#include <hip/hip_runtime.h>
#include <math.h>

// Problem constants (B,C,T,H,W)=(4,3,12,256,256), CH0=32
#define HW_    65536
#define THW_   786432      // T*H*W
#define NP     262144      // B*H*W pixels
#define N1_    3145728.0   // B*T*H*W
#define N3_    262144.0    // B*H*W

// dws shard layout (doubles):
//   XB: x-stats, 9 q x 8 shards    [0,72)
//   SB: h-stats, 132 q x 8 shards  [72,1128)  q=o*4+{mn,mn2,mx,mx2}; 128..131=Srt,SSrt,Stt,SStt
//   EB: enc-stats, 256 q x 4 shards[1128,2152) q=(b*32+o)*2+{S,SS}
#define XB 0
#define SB 72
#define EB 1128
#define DWN 2152

__device__ __constant__ float PW_[5] = {-0.33647654f, 0.20279402f, 0.77575913f, 0.20279402f, -0.33647654f};
__device__ __constant__ float RW_[5] = {-0.2f, -0.1f, 0.0f, 0.1f, 0.2f};

typedef __fp16 fp16x2 __attribute__((ext_vector_type(2)));
union H2U { fp16x2 h; unsigned int u; };
__device__ __forceinline__ unsigned int packh(float a, float b) {
  H2U x; x.h = __builtin_amdgcn_cvt_pkrtz(a, b); return x.u;
}
__device__ __forceinline__ float2 unpackh(unsigned int v) {
  H2U x; x.u = v; return make_float2((float)x.h.x, (float)x.h.y);
}
__device__ __forceinline__ unsigned short pack1h(float a) {
  return (unsigned short)(packh(a, 0.f) & 0xffffu);
}

__device__ __forceinline__ float wred64(float v) {
#pragma unroll
  for (int m = 32; m > 0; m >>= 1) v += __shfl_xor(v, m, 64);
  return v;
}

__device__ __forceinline__ float fsilu(float y) {
  float e = __expf(-y);
  return y * __builtin_amdgcn_rcpf(1.0f + e);
}

// x statistics: 3072 blocks, each handles 256 consecutive float4 of one b.
__global__ __launch_bounds__(256) void k_xstats(const float* __restrict__ x, double* __restrict__ dws) {
  const int b = blockIdx.x & 3;
  const int v = (blockIdx.x >> 2) * 256 + threadIdx.x;   // [0,196608)
  const float4* x4 = (const float4*)x;
  float4 a0 = x4[(size_t)(b * 3 + 0) * 196608 + v];
  float4 a1 = x4[(size_t)(b * 3 + 1) * 196608 + v];
  float4 a2 = x4[(size_t)(b * 3 + 2) * 196608 + v];
  float s0 = a0.x + a0.y + a0.z + a0.w;
  float s1 = a1.x + a1.y + a1.z + a1.w;
  float s2 = a2.x + a2.y + a2.z + a2.w;
  float p00 = a0.x * a0.x + a0.y * a0.y + a0.z * a0.z + a0.w * a0.w;
  float p11 = a1.x * a1.x + a1.y * a1.y + a1.z * a1.z + a1.w * a1.w;
  float p22 = a2.x * a2.x + a2.y * a2.y + a2.z * a2.z + a2.w * a2.w;
  float p01 = a0.x * a1.x + a0.y * a1.y + a0.z * a1.z + a0.w * a1.w;
  float p02 = a0.x * a2.x + a0.y * a2.y + a0.z * a2.z + a0.w * a2.w;
  float p12 = a1.x * a2.x + a1.y * a2.y + a1.z * a2.z + a1.w * a2.w;
  float vals[9] = {s0, s1, s2, p00, p01, p02, p11, p12, p22};
  __shared__ float red[4][9];
  int wave = threadIdx.x >> 6, lane = threadIdx.x & 63;
#pragma unroll
  for (int q = 0; q < 9; q++) vals[q] = wred64(vals[q]);
  if (lane == 0) {
#pragma unroll
    for (int q = 0; q < 9; q++) red[wave][q] = vals[q];
  }
  __syncthreads();
  if (threadIdx.x < 9) {
    double t = (double)red[0][threadIdx.x] + red[1][threadIdx.x] + red[2][threadIdx.x] + red[3][threadIdx.x];
    atomicAdd(&dws[XB + threadIdx.x * 8 + (blockIdx.x & 7)], t);
  }
}

// passB: fin0 prologue + lean round-3 body + cheap fused rt/tt stats.
__global__ __launch_bounds__(256) void k_passB(const float* __restrict__ x, const float* __restrict__ wrt,
                                               const float* __restrict__ wtt, const float* __restrict__ w0,
                                               const float* __restrict__ g0, const float* __restrict__ b0,
                                               unsigned int* __restrict__ pRT, unsigned int* __restrict__ pMM,
                                               double* __restrict__ dws) {
  const int tid = threadIdx.x;
  const int pix = blockIdx.x * 256 + tid;
  const int b = pix >> 16, hw = pix & 65535;
  __shared__ float red[4][4];
  __shared__ float cfa0[32], cfa1[32], cfa2[32], cfb[32];

  if (tid < 32) {
    int o = tid;
    double q[9];
#pragma unroll
    for (int i = 0; i < 9; i++) {
      double t = 0;
#pragma unroll
      for (int s = 0; s < 8; s++) t += dws[XB + i * 8 + s];
      q[i] = t / N1_;
    }
    double c0 = w0[o * 3 + 0], c1 = w0[o * 3 + 1], c2 = w0[o * 3 + 2];
    double Ey = c0 * q[0] + c1 * q[1] + c2 * q[2];
    double Ey2 = c0 * c0 * q[3] + c1 * c1 * q[6] + c2 * c2 * q[8] +
                 2.0 * (c0 * c1 * q[4] + c0 * c2 * q[5] + c1 * c2 * q[7]);
    double var = Ey2 - Ey * Ey;
    double alpha = (double)g0[o] / sqrt(var + 1e-5);
    cfa0[o] = (float)(alpha * c0);
    cfa1[o] = (float)(alpha * c1);
    cfa2[o] = (float)(alpha * c2);
    cfb[o]  = (float)((double)b0[o] - Ey * alpha);
  }
  __syncthreads();

  const float* xp = x + (size_t)b * 3 * THW_ + hw;
  float xv[3][12];
#pragma unroll
  for (int c = 0; c < 3; c++)
#pragma unroll
    for (int t = 0; t < 12; t++) xv[c][t] = xp[(size_t)(c * 12 + t) * HW_];
  float wt[3] = {wtt[0], wtt[1], wtt[2]};
  float ttp[12];
#pragma unroll
  for (int t = 0; t < 12; t++) {
    float acc = 0.f;
#pragma unroll
    for (int c = 0; c < 3; c++) {
      float pk = 0.f, sl = 0.f;
#pragma unroll
      for (int j = 0; j < 5; j++) {
        int tj = t - 2 + j;
        if (tj >= 0 && tj < 12) {
          pk = fmaf(PW_[j], xv[c][tj], pk);
          sl = fmaf(RW_[j], xv[c][tj], sl);
        }
      }
      acc = fmaf(wt[c], pk + fabsf(sl), acc);
    }
    ttp[t] = acc;
  }
  float rt_t[12];
#pragma unroll
  for (int t = 0; t < 12; t++) rt_t[t] = 0.f;
#pragma unroll
  for (int o = 0; o < 32; o++) {
    float a0 = cfa0[o], a1 = cfa1[o], a2 = cfa2[o];
    float bet = cfb[o], wo = wrt[o];
    float mn = 3.4e38f, mx = -3.4e38f;
#pragma unroll
    for (int t = 0; t < 12; t++) {
      float y = fmaf(a0, xv[0][t], fmaf(a1, xv[1][t], fmaf(a2, xv[2][t], bet)));
      float h = fsilu(y);
      mn = fminf(mn, h);
      mx = fmaxf(mx, h);
      rt_t[t] = fmaf(wo, h, rt_t[t]);
    }
    pMM[o * NP + pix] = packh(mn, mx);
  }
#pragma unroll
  for (int t = 0; t < 12; t++) pRT[t * NP + pix] = packh(rt_t[t], ttp[t]);

  // rt/tt scalar stats (cheap: 4 wred64)
  {
    float srt = 0.f, ssrt = 0.f, stt = 0.f, sstt = 0.f;
#pragma unroll
    for (int t = 0; t < 12; t++) {
      srt += rt_t[t];  ssrt = fmaf(rt_t[t], rt_t[t], ssrt);
      stt += ttp[t];   sstt = fmaf(ttp[t], ttp[t], sstt);
    }
    srt = wred64(srt); ssrt = wred64(ssrt); stt = wred64(stt); sstt = wred64(sstt);
    int wave = tid >> 6, lane = tid & 63;
    if (lane == 0) { red[wave][0] = srt; red[wave][1] = ssrt; red[wave][2] = stt; red[wave][3] = sstt; }
  }
  __syncthreads();
  if (tid < 4) {
    double v = (double)red[0][tid] + red[1][tid] + red[2][tid] + red[3][tid];
    atomicAdd(&dws[SB + (128 + tid) * 8 + (blockIdx.x & 7)], v);
  }
}

// min/max stats over pMM: 1024 blocks (32 per o); pMM is L2/L3-resident.
__global__ __launch_bounds__(256) void k_stats(const unsigned int* __restrict__ pMM,
                                               double* __restrict__ dws) {
  __shared__ float red[4][4];
  int o = blockIdx.x >> 5, sub = blockIdx.x & 31, tid = threadIdx.x;
  const uint4* p = (const uint4*)(pMM + (size_t)o * NP);   // 65536 uint4 per o
  int base = sub * 256 + tid;
  float s0 = 0, s1 = 0, s2 = 0, s3 = 0;
#pragma unroll
  for (int it = 0; it < 8; it++) {
    uint4 v = p[base + it * 8192];
    float2 a = unpackh(v.x), b = unpackh(v.y), c = unpackh(v.z), d = unpackh(v.w);
    s0 += a.x + b.x + c.x + d.x;
    s1 += a.x * a.x + b.x * b.x + c.x * c.x + d.x * d.x;
    s2 += a.y + b.y + c.y + d.y;
    s3 += a.y * a.y + b.y * b.y + c.y * c.y + d.y * d.y;
  }
  s0 = wred64(s0); s1 = wred64(s1); s2 = wred64(s2); s3 = wred64(s3);
  int wave = tid >> 6, lane = tid & 63;
  if (lane == 0) { red[wave][0] = s0; red[wave][1] = s1; red[wave][2] = s2; red[wave][3] = s3; }
  __syncthreads();
  if (tid < 4) {
    double v = (double)red[0][tid] + red[1][tid] + red[2][tid] + red[3][tid];
    atomicAdd(&dws[SB + (o * 4 + tid) * 8 + (blockIdx.x & 7)], v);
  }
}

// passC: finB prologue + enc assembly; fp16 enc to penc (or f32 fallback).
template<bool FP16OUT>
__global__ __launch_bounds__(256) void k_passC(const unsigned int* __restrict__ pRT,
                                               const unsigned int* __restrict__ pMM,
                                               const float* __restrict__ wth, const float* __restrict__ bth,
                                               const float* __restrict__ grt, const float* __restrict__ brt,
                                               const float* __restrict__ gtt, const float* __restrict__ btt,
                                               const float* __restrict__ gmin, const float* __restrict__ bmin,
                                               const float* __restrict__ gmax, const float* __restrict__ bmax,
                                               const float* __restrict__ gmean, const float* __restrict__ bmean,
                                               const double* __restrict__ dws, float* __restrict__ out,
                                               unsigned short* __restrict__ penc) {
  const int tid = threadIdx.x;
  const int pix = blockIdx.x * 256 + tid;
  const int b = pix >> 16, hw = pix & 65535;
  __shared__ float camn[32], cbmn[32], camx[32], cbmx[32], came[32], cbme[32];
  __shared__ float c4[4];

  if (tid < 32) {
    double q[4];
#pragma unroll
    for (int i = 0; i < 4; i++) {
      double t = 0;
#pragma unroll
      for (int s = 0; s < 8; s++) t += dws[SB + (tid * 4 + i) * 8 + s];
      q[i] = t / N3_;
    }
    double m = q[0], v = q[1] - m * m;
    double a = (double)gmin[tid] / sqrt(v + 1e-5);
    camn[tid] = (float)a; cbmn[tid] = (float)((double)bmin[tid] - m * a);
    double mm = q[2], vv = q[3] - mm * mm;
    a = (double)gmax[tid] / sqrt(vv + 1e-5);
    camx[tid] = (float)a; cbmx[tid] = (float)((double)bmax[tid] - mm * a);
    a = (double)gmean[tid] / sqrt(vv + 1e-5);
    came[tid] = (float)a; cbme[tid] = (float)((double)bmean[tid] - mm * a);
  }
  if (tid == 32) {
    double q[4];
#pragma unroll
    for (int i = 0; i < 4; i++) {
      double t = 0;
#pragma unroll
      for (int s = 0; s < 8; s++) t += dws[SB + (128 + i) * 8 + s];
      q[i] = t / N1_;
    }
    double m = q[0], v = q[1] - m * m;
    double a = (double)grt[0] / sqrt(v + 1e-5);
    c4[0] = (float)a; c4[1] = (float)((double)brt[0] - m * a);
    m = q[2]; v = q[3] - m * m;
    a = (double)gtt[0] / sqrt(v + 1e-5);
    c4[2] = (float)a; c4[3] = (float)((double)btt[0] - m * a);
  }
  __syncthreads();

  float art = c4[0], brt_ = c4[1], att = c4[2], btt_ = c4[3];
  float rtt[12];
#pragma unroll
  for (int t = 0; t < 12; t++) {
    float2 v = unpackh(pRT[t * NP + pix]);
    rtt[t] = fsilu(fmaf(art, v.x, brt_)) + fsilu(fmaf(att, v.y, btt_));
  }
  float* po = out + (size_t)b * 32 * HW_ + hw;
  unsigned short* pe = penc + ((size_t)(b * 32) << 16) + hw;
#pragma unroll
  for (int o = 0; o < 32; o++) {
    float2 mm = unpackh(pMM[o * NP + pix]);
    float tl = bth[o];
#pragma unroll
    for (int t = 0; t < 12; t++) tl = fmaf(wth[o * 12 + t], rtt[t], tl);
    float e = tl + fsilu(fmaf(camn[o], mm.x, cbmn[o]))
                 + fsilu(fmaf(camx[o], mm.y, cbmx[o]))
                 + fsilu(fmaf(came[o], mm.y, cbme[o]));
    if (FP16OUT) pe[(size_t)o << 16] = pack1h(e);
    else         po[(size_t)o * HW_] = e;
  }
}

// enc stats, fp16 source (4 blocks per slice)
__global__ __launch_bounds__(256) void k_encstats16(const unsigned short* __restrict__ penc,
                                                    double* __restrict__ dws) {
  __shared__ float red[4][2];
  int s = blockIdx.x >> 2, sub = blockIdx.x & 3, tid = threadIdx.x;
  const uint4* p = (const uint4*)(penc + ((size_t)s << 16));   // 8192 uint4 per slice
  float S = 0, SS = 0;
#pragma unroll
  for (int it = 0; it < 8; it++) {
    uint4 v = p[sub * 2048 + tid + it * 256];
    float2 a = unpackh(v.x), b = unpackh(v.y), c = unpackh(v.z), d = unpackh(v.w);
    S += a.x + a.y + b.x + b.y + c.x + c.y + d.x + d.y;
    SS += a.x * a.x + a.y * a.y + b.x * b.x + b.y * b.y +
          c.x * c.x + c.y * c.y + d.x * d.x + d.y * d.y;
  }
  S = wred64(S); SS = wred64(SS);
  int wave = tid >> 6, lane = tid & 63;
  if (lane == 0) { red[wave][0] = S; red[wave][1] = SS; }
  __syncthreads();
  if (tid < 2) {
    double v = (double)red[0][tid] + red[1][tid] + red[2][tid] + red[3][tid];
    atomicAdd(&dws[EB + (s * 2 + tid) * 4 + sub], v);
  }
}

__global__ __launch_bounds__(256) void k_inorm16(const double* __restrict__ dws,
                                                 const unsigned short* __restrict__ penc,
                                                 float* __restrict__ out) {
  int s = blockIdx.y;
  double S = 0, SS = 0;
#pragma unroll
  for (int sh = 0; sh < 4; sh++) {
    S  += dws[EB + (s * 2 + 0) * 4 + sh];
    SS += dws[EB + (s * 2 + 1) * 4 + sh];
  }
  double m = S / 65536.0, v = SS / 65536.0 - m * m;
  float rstd = (float)(1.0 / sqrt(v + 1e-5));
  float mf = (float)m;
  const uint2* p = (const uint2*)(penc + ((size_t)s << 16));   // 16384 uint2
  float4* po = (float4*)(out + ((size_t)s << 16));
  int i = blockIdx.x * 256 + threadIdx.x;
  uint2 u = p[i];
  float2 a = unpackh(u.x), b = unpackh(u.y);
  float4 r;
  r.x = (a.x - mf) * rstd;
  r.y = (a.y - mf) * rstd;
  r.z = (b.x - mf) * rstd;
  r.w = (b.y - mf) * rstd;
  po[i] = r;
}

// f32 fallback tail
__global__ __launch_bounds__(256) void k_encstats32(const float* __restrict__ out, double* __restrict__ dws) {
  __shared__ float red[4][2];
  int s = blockIdx.x >> 2, sub = blockIdx.x & 3, tid = threadIdx.x;
  const float4* p = (const float4*)(out + ((size_t)s << 16));
  float S = 0, SS = 0;
#pragma unroll 4
  for (int it = 0; it < 16; it++) {
    float4 a = p[sub * 256 + tid + it * 1024];
    S += a.x + a.y + a.z + a.w;
    SS += a.x * a.x + a.y * a.y + a.z * a.z + a.w * a.w;
  }
  S = wred64(S); SS = wred64(SS);
  int wave = tid >> 6, lane = tid & 63;
  if (lane == 0) { red[wave][0] = S; red[wave][1] = SS; }
  __syncthreads();
  if (tid < 2) {
    double v = (double)red[0][tid] + red[1][tid] + red[2][tid] + red[3][tid];
    atomicAdd(&dws[EB + (s * 2 + tid) * 4 + sub], v);
  }
}

__global__ __launch_bounds__(256) void k_inorm32(const double* __restrict__ dws, float* __restrict__ out) {
  int s = blockIdx.y;
  double S = 0, SS = 0;
#pragma unroll
  for (int sh = 0; sh < 4; sh++) {
    S  += dws[EB + (s * 2 + 0) * 4 + sh];
    SS += dws[EB + (s * 2 + 1) * 4 + sh];
  }
  double m = S / 65536.0, v = SS / 65536.0 - m * m;
  float rstd = (float)(1.0 / sqrt(v + 1e-5));
  float mf = (float)m;
  float4* p = (float4*)(out + ((size_t)s << 16));
  int i = blockIdx.x * 256 + threadIdx.x;
  float4 a = p[i];
  a.x = (a.x - mf) * rstd;
  a.y = (a.y - mf) * rstd;
  a.z = (a.z - mf) * rstd;
  a.w = (a.w - mf) * rstd;
  p[i] = a;
}

extern "C" void kernel_launch(void* const* d_in, const int* in_sizes, int n_in,
                              void* d_out, int out_size, void* d_ws, size_t ws_size,
                              hipStream_t stream) {
  const float* x     = (const float*)d_in[0];
  const float* w0    = (const float*)d_in[1];
  const float* g0    = (const float*)d_in[2];
  const float* b0    = (const float*)d_in[3];
  const float* wrt   = (const float*)d_in[4];
  const float* grt   = (const float*)d_in[5];
  const float* brt   = (const float*)d_in[6];
  const float* wtt   = (const float*)d_in[7];
  const float* gtt   = (const float*)d_in[8];
  const float* btt   = (const float*)d_in[9];
  const float* wth   = (const float*)d_in[10];
  const float* bth   = (const float*)d_in[11];
  const float* gmin  = (const float*)d_in[12];
  const float* bmin  = (const float*)d_in[13];
  const float* gmax  = (const float*)d_in[14];
  const float* bmax  = (const float*)d_in[15];
  const float* gmean = (const float*)d_in[16];
  const float* bmean = (const float*)d_in[17];
  double* dws = (double*)d_ws;
  unsigned int* pRT = (unsigned int*)((char*)d_ws + 65536);
  unsigned int* pMM = pRT + 12 * NP;
  unsigned short* pENC = (unsigned short*)(pMM + 32 * NP);
  const size_t need16 = 65536 + (size_t)12 * NP * 4 + (size_t)32 * NP * 4 + (size_t)32 * NP * 2;
  const bool big = ws_size >= need16;
  float* out = (float*)d_out;

  hipMemsetAsync(d_ws, 0, DWN * sizeof(double), stream);
  hipLaunchKernelGGL(k_xstats, dim3(3072), dim3(256), 0, stream, x, dws);
  hipLaunchKernelGGL(k_passB, dim3(1024), dim3(256), 0, stream, x, wrt, wtt, w0, g0, b0, pRT, pMM, dws);
  hipLaunchKernelGGL(k_stats, dim3(1024), dim3(256), 0, stream, pMM, dws);
  if (big) {
    hipLaunchKernelGGL((k_passC<true>), dim3(1024), dim3(256), 0, stream, pRT, pMM, wth, bth,
                       grt, brt, gtt, btt, gmin, bmin, gmax, bmax, gmean, bmean, dws, out, pENC);
    hipLaunchKernelGGL(k_encstats16, dim3(512), dim3(256), 0, stream, pENC, dws);
    hipLaunchKernelGGL(k_inorm16, dim3(64, 128), dim3(256), 0, stream, dws, pENC, out);
  } else {
    hipLaunchKernelGGL((k_passC<false>), dim3(1024), dim3(256), 0, stream, pRT, pMM, wth, bth,
                       grt, brt, gtt, btt, gmin, bmin, gmax, bmax, gmean, bmean, dws, out, pENC);
    hipLaunchKernelGGL(k_encstats32, dim3(512), dim3(256), 0, stream, out, dws);
    hipLaunchKernelGGL(k_inorm32, dim3(64, 128), dim3(256), 0, stream, dws, out);
  }
}

// Round 12
// 103.234 us; speedup vs baseline: 1.5975x; 1.5975x over previous
//
#include <hip/hip_runtime.h>
#include <math.h>

// Problem constants (B,C,T,H,W)=(4,3,12,256,256), CH0=32
#define HW_    65536
#define THW_   786432      // T*H*W
#define NP     262144      // B*H*W pixels
#define N1_    3145728.0   // B*T*H*W
#define N3_    262144.0    // B*H*W

// dws shard layout (doubles) — shards are CACHE-LINE SEPARATED where writer
// count is high:
//   XB: x-stats, 9 q; 32 shards, slot = XB + s*16 + i         [0,512)
//   SB: h min/max stats, 128 q x 8 dense shards, q*8+s        [512,1536)
//   RB: rt/tt stats, 4 q; 32 shards, slot = RB + s*8 + j      [1536,1792)
//   EB: enc-stats, 256 q x 4 dense shards, q*4+s              [1792,2816)
#define XB 0
#define SB 512
#define RB 1536
#define EB 1792
#define DWN 2816

__device__ __constant__ float PW_[5] = {-0.33647654f, 0.20279402f, 0.77575913f, 0.20279402f, -0.33647654f};
__device__ __constant__ float RW_[5] = {-0.2f, -0.1f, 0.0f, 0.1f, 0.2f};

typedef __fp16 fp16x2 __attribute__((ext_vector_type(2)));
union H2U { fp16x2 h; unsigned int u; };
__device__ __forceinline__ unsigned int packh(float a, float b) {
  H2U x; x.h = __builtin_amdgcn_cvt_pkrtz(a, b); return x.u;
}
__device__ __forceinline__ float2 unpackh(unsigned int v) {
  H2U x; x.u = v; return make_float2((float)x.h.x, (float)x.h.y);
}
__device__ __forceinline__ unsigned short pack1h(float a) {
  return (unsigned short)(packh(a, 0.f) & 0xffffu);
}

__device__ __forceinline__ float wred64(float v) {
#pragma unroll
  for (int m = 32; m > 0; m >>= 1) v += __shfl_xor(v, m, 64);
  return v;
}

__device__ __forceinline__ float fsilu(float y) {
  float e = __expf(-y);
  return y * __builtin_amdgcn_rcpf(1.0f + e);
}

// x statistics: round-10 proven grid (768 blocks, 12 float4 loads/thread);
// atomics go to 32 line-separated shards.
__global__ __launch_bounds__(256) void k_xstats(const float* __restrict__ x, double* __restrict__ dws) {
  const int v = blockIdx.x * 256 + threadIdx.x;   // float4 index in [0,196608)
  const float4* x4 = (const float4*)x;
  float s0 = 0, s1 = 0, s2 = 0, p00 = 0, p01 = 0, p02 = 0, p11 = 0, p12 = 0, p22 = 0;
#pragma unroll
  for (int b = 0; b < 4; b++) {
    float4 a0 = x4[(size_t)(b * 3 + 0) * 196608 + v];
    float4 a1 = x4[(size_t)(b * 3 + 1) * 196608 + v];
    float4 a2 = x4[(size_t)(b * 3 + 2) * 196608 + v];
    s0 += a0.x + a0.y + a0.z + a0.w;
    s1 += a1.x + a1.y + a1.z + a1.w;
    s2 += a2.x + a2.y + a2.z + a2.w;
    p00 += a0.x * a0.x + a0.y * a0.y + a0.z * a0.z + a0.w * a0.w;
    p11 += a1.x * a1.x + a1.y * a1.y + a1.z * a1.z + a1.w * a1.w;
    p22 += a2.x * a2.x + a2.y * a2.y + a2.z * a2.z + a2.w * a2.w;
    p01 += a0.x * a1.x + a0.y * a1.y + a0.z * a1.z + a0.w * a1.w;
    p02 += a0.x * a2.x + a0.y * a2.y + a0.z * a2.z + a0.w * a2.w;
    p12 += a1.x * a2.x + a1.y * a2.y + a1.z * a2.z + a1.w * a2.w;
  }
  float vals[9] = {s0, s1, s2, p00, p01, p02, p11, p12, p22};
  __shared__ float red[4][9];
  int wave = threadIdx.x >> 6, lane = threadIdx.x & 63;
#pragma unroll
  for (int q = 0; q < 9; q++) vals[q] = wred64(vals[q]);
  if (lane == 0) {
#pragma unroll
    for (int q = 0; q < 9; q++) red[wave][q] = vals[q];
  }
  __syncthreads();
  if (threadIdx.x < 9) {
    double t = (double)red[0][threadIdx.x] + red[1][threadIdx.x] + red[2][threadIdx.x] + red[3][threadIdx.x];
    atomicAdd(&dws[XB + (blockIdx.x & 31) * 16 + threadIdx.x], t);
  }
}

// passB: fin0 prologue + lean body + cheap fused rt/tt stats (line-sep shards).
__global__ __launch_bounds__(256) void k_passB(const float* __restrict__ x, const float* __restrict__ wrt,
                                               const float* __restrict__ wtt, const float* __restrict__ w0,
                                               const float* __restrict__ g0, const float* __restrict__ b0,
                                               unsigned int* __restrict__ pRT, unsigned int* __restrict__ pMM,
                                               double* __restrict__ dws) {
  const int tid = threadIdx.x;
  const int pix = blockIdx.x * 256 + tid;
  const int b = pix >> 16, hw = pix & 65535;
  __shared__ float red[4][4];
  __shared__ float cfa0[32], cfa1[32], cfa2[32], cfb[32];

  if (tid < 32) {
    int o = tid;
    double q[9];
#pragma unroll
    for (int i = 0; i < 9; i++) {
      double t = 0;
#pragma unroll
      for (int s = 0; s < 32; s++) t += dws[XB + s * 16 + i];
      q[i] = t / N1_;
    }
    double c0 = w0[o * 3 + 0], c1 = w0[o * 3 + 1], c2 = w0[o * 3 + 2];
    double Ey = c0 * q[0] + c1 * q[1] + c2 * q[2];
    double Ey2 = c0 * c0 * q[3] + c1 * c1 * q[6] + c2 * c2 * q[8] +
                 2.0 * (c0 * c1 * q[4] + c0 * c2 * q[5] + c1 * c2 * q[7]);
    double var = Ey2 - Ey * Ey;
    double alpha = (double)g0[o] / sqrt(var + 1e-5);
    cfa0[o] = (float)(alpha * c0);
    cfa1[o] = (float)(alpha * c1);
    cfa2[o] = (float)(alpha * c2);
    cfb[o]  = (float)((double)b0[o] - Ey * alpha);
  }
  __syncthreads();

  const float* xp = x + (size_t)b * 3 * THW_ + hw;
  float xv[3][12];
#pragma unroll
  for (int c = 0; c < 3; c++)
#pragma unroll
    for (int t = 0; t < 12; t++) xv[c][t] = xp[(size_t)(c * 12 + t) * HW_];
  float wt[3] = {wtt[0], wtt[1], wtt[2]};
  float ttp[12];
#pragma unroll
  for (int t = 0; t < 12; t++) {
    float acc = 0.f;
#pragma unroll
    for (int c = 0; c < 3; c++) {
      float pk = 0.f, sl = 0.f;
#pragma unroll
      for (int j = 0; j < 5; j++) {
        int tj = t - 2 + j;
        if (tj >= 0 && tj < 12) {
          pk = fmaf(PW_[j], xv[c][tj], pk);
          sl = fmaf(RW_[j], xv[c][tj], sl);
        }
      }
      acc = fmaf(wt[c], pk + fabsf(sl), acc);
    }
    ttp[t] = acc;
  }
  float rt_t[12];
#pragma unroll
  for (int t = 0; t < 12; t++) rt_t[t] = 0.f;
#pragma unroll
  for (int o = 0; o < 32; o++) {
    float a0 = cfa0[o], a1 = cfa1[o], a2 = cfa2[o];
    float bet = cfb[o], wo = wrt[o];
    float mn = 3.4e38f, mx = -3.4e38f;
#pragma unroll
    for (int t = 0; t < 12; t++) {
      float y = fmaf(a0, xv[0][t], fmaf(a1, xv[1][t], fmaf(a2, xv[2][t], bet)));
      float h = fsilu(y);
      mn = fminf(mn, h);
      mx = fmaxf(mx, h);
      rt_t[t] = fmaf(wo, h, rt_t[t]);
    }
    pMM[o * NP + pix] = packh(mn, mx);
  }
#pragma unroll
  for (int t = 0; t < 12; t++) pRT[t * NP + pix] = packh(rt_t[t], ttp[t]);

  // rt/tt scalar stats -> 32 line-separated shards
  {
    float srt = 0.f, ssrt = 0.f, stt = 0.f, sstt = 0.f;
#pragma unroll
    for (int t = 0; t < 12; t++) {
      srt += rt_t[t];  ssrt = fmaf(rt_t[t], rt_t[t], ssrt);
      stt += ttp[t];   sstt = fmaf(ttp[t], ttp[t], sstt);
    }
    srt = wred64(srt); ssrt = wred64(ssrt); stt = wred64(stt); sstt = wred64(sstt);
    int wave = tid >> 6, lane = tid & 63;
    if (lane == 0) { red[wave][0] = srt; red[wave][1] = ssrt; red[wave][2] = stt; red[wave][3] = sstt; }
  }
  __syncthreads();
  if (tid < 4) {
    double v = (double)red[0][tid] + red[1][tid] + red[2][tid] + red[3][tid];
    atomicAdd(&dws[RB + (blockIdx.x & 31) * 8 + tid], v);
  }
}

// min/max stats over pMM: 1024 blocks (32 per o); pMM is L2/L3-resident.
__global__ __launch_bounds__(256) void k_stats(const unsigned int* __restrict__ pMM,
                                               double* __restrict__ dws) {
  __shared__ float red[4][4];
  int o = blockIdx.x >> 5, sub = blockIdx.x & 31, tid = threadIdx.x;
  const uint4* p = (const uint4*)(pMM + (size_t)o * NP);   // 65536 uint4 per o
  int base = sub * 256 + tid;
  float s0 = 0, s1 = 0, s2 = 0, s3 = 0;
#pragma unroll
  for (int it = 0; it < 8; it++) {
    uint4 v = p[base + it * 8192];
    float2 a = unpackh(v.x), b = unpackh(v.y), c = unpackh(v.z), d = unpackh(v.w);
    s0 += a.x + b.x + c.x + d.x;
    s1 += a.x * a.x + b.x * b.x + c.x * c.x + d.x * d.x;
    s2 += a.y + b.y + c.y + d.y;
    s3 += a.y * a.y + b.y * b.y + c.y * c.y + d.y * d.y;
  }
  s0 = wred64(s0); s1 = wred64(s1); s2 = wred64(s2); s3 = wred64(s3);
  int wave = tid >> 6, lane = tid & 63;
  if (lane == 0) { red[wave][0] = s0; red[wave][1] = s1; red[wave][2] = s2; red[wave][3] = s3; }
  __syncthreads();
  if (tid < 4) {
    double v = (double)red[0][tid] + red[1][tid] + red[2][tid] + red[3][tid];
    atomicAdd(&dws[SB + (o * 4 + tid) * 8 + (blockIdx.x & 7)], v);
  }
}

// passC: finB prologue + enc assembly; fp16 enc to penc (or f32 fallback).
template<bool FP16OUT>
__global__ __launch_bounds__(256) void k_passC(const unsigned int* __restrict__ pRT,
                                               const unsigned int* __restrict__ pMM,
                                               const float* __restrict__ wth, const float* __restrict__ bth,
                                               const float* __restrict__ grt, const float* __restrict__ brt,
                                               const float* __restrict__ gtt, const float* __restrict__ btt,
                                               const float* __restrict__ gmin, const float* __restrict__ bmin,
                                               const float* __restrict__ gmax, const float* __restrict__ bmax,
                                               const float* __restrict__ gmean, const float* __restrict__ bmean,
                                               const double* __restrict__ dws, float* __restrict__ out,
                                               unsigned short* __restrict__ penc) {
  const int tid = threadIdx.x;
  const int pix = blockIdx.x * 256 + tid;
  const int b = pix >> 16, hw = pix & 65535;
  __shared__ float camn[32], cbmn[32], camx[32], cbmx[32], came[32], cbme[32];
  __shared__ float c4[4];

  if (tid < 32) {
    double q[4];
#pragma unroll
    for (int i = 0; i < 4; i++) {
      double t = 0;
#pragma unroll
      for (int s = 0; s < 8; s++) t += dws[SB + (tid * 4 + i) * 8 + s];
      q[i] = t / N3_;
    }
    double m = q[0], v = q[1] - m * m;
    double a = (double)gmin[tid] / sqrt(v + 1e-5);
    camn[tid] = (float)a; cbmn[tid] = (float)((double)bmin[tid] - m * a);
    double mm = q[2], vv = q[3] - mm * mm;
    a = (double)gmax[tid] / sqrt(vv + 1e-5);
    camx[tid] = (float)a; cbmx[tid] = (float)((double)bmax[tid] - mm * a);
    a = (double)gmean[tid] / sqrt(vv + 1e-5);
    came[tid] = (float)a; cbme[tid] = (float)((double)bmean[tid] - mm * a);
  }
  if (tid == 32) {
    double q[4];
#pragma unroll
    for (int i = 0; i < 4; i++) {
      double t = 0;
#pragma unroll
      for (int s = 0; s < 32; s++) t += dws[RB + s * 8 + i];
      q[i] = t / N1_;
    }
    double m = q[0], v = q[1] - m * m;
    double a = (double)grt[0] / sqrt(v + 1e-5);
    c4[0] = (float)a; c4[1] = (float)((double)brt[0] - m * a);
    m = q[2]; v = q[3] - m * m;
    a = (double)gtt[0] / sqrt(v + 1e-5);
    c4[2] = (float)a; c4[3] = (float)((double)btt[0] - m * a);
  }
  __syncthreads();

  float art = c4[0], brt_ = c4[1], att = c4[2], btt_ = c4[3];
  float rtt[12];
#pragma unroll
  for (int t = 0; t < 12; t++) {
    float2 v = unpackh(pRT[t * NP + pix]);
    rtt[t] = fsilu(fmaf(art, v.x, brt_)) + fsilu(fmaf(att, v.y, btt_));
  }
  float* po = out + (size_t)b * 32 * HW_ + hw;
  unsigned short* pe = penc + ((size_t)(b * 32) << 16) + hw;
#pragma unroll
  for (int o = 0; o < 32; o++) {
    float2 mm = unpackh(pMM[o * NP + pix]);
    float tl = bth[o];
#pragma unroll
    for (int t = 0; t < 12; t++) tl = fmaf(wth[o * 12 + t], rtt[t], tl);
    float e = tl + fsilu(fmaf(camn[o], mm.x, cbmn[o]))
                 + fsilu(fmaf(camx[o], mm.y, cbmx[o]))
                 + fsilu(fmaf(came[o], mm.y, cbme[o]));
    if (FP16OUT) pe[(size_t)o << 16] = pack1h(e);
    else         po[(size_t)o * HW_] = e;
  }
}

// enc stats, fp16 source (4 blocks per slice)
__global__ __launch_bounds__(256) void k_encstats16(const unsigned short* __restrict__ penc,
                                                    double* __restrict__ dws) {
  __shared__ float red[4][2];
  int s = blockIdx.x >> 2, sub = blockIdx.x & 3, tid = threadIdx.x;
  const uint4* p = (const uint4*)(penc + ((size_t)s << 16));   // 8192 uint4 per slice
  float S = 0, SS = 0;
#pragma unroll
  for (int it = 0; it < 8; it++) {
    uint4 v = p[sub * 2048 + tid + it * 256];
    float2 a = unpackh(v.x), b = unpackh(v.y), c = unpackh(v.z), d = unpackh(v.w);
    S += a.x + a.y + b.x + b.y + c.x + c.y + d.x + d.y;
    SS += a.x * a.x + a.y * a.y + b.x * b.x + b.y * b.y +
          c.x * c.x + c.y * c.y + d.x * d.x + d.y * d.y;
  }
  S = wred64(S); SS = wred64(SS);
  int wave = tid >> 6, lane = tid & 63;
  if (lane == 0) { red[wave][0] = S; red[wave][1] = SS; }
  __syncthreads();
  if (tid < 2) {
    double v = (double)red[0][tid] + red[1][tid] + red[2][tid] + red[3][tid];
    atomicAdd(&dws[EB + (s * 2 + tid) * 4 + sub], v);
  }
}

__global__ __launch_bounds__(256) void k_inorm16(const double* __restrict__ dws,
                                                 const unsigned short* __restrict__ penc,
                                                 float* __restrict__ out) {
  int s = blockIdx.y;
  double S = 0, SS = 0;
#pragma unroll
  for (int sh = 0; sh < 4; sh++) {
    S  += dws[EB + (s * 2 + 0) * 4 + sh];
    SS += dws[EB + (s * 2 + 1) * 4 + sh];
  }
  double m = S / 65536.0, v = SS / 65536.0 - m * m;
  float rstd = (float)(1.0 / sqrt(v + 1e-5));
  float mf = (float)m;
  const uint2* p = (const uint2*)(penc + ((size_t)s << 16));   // 16384 uint2
  float4* po = (float4*)(out + ((size_t)s << 16));
  int i = blockIdx.x * 256 + threadIdx.x;
  uint2 u = p[i];
  float2 a = unpackh(u.x), b = unpackh(u.y);
  float4 r;
  r.x = (a.x - mf) * rstd;
  r.y = (a.y - mf) * rstd;
  r.z = (b.x - mf) * rstd;
  r.w = (b.y - mf) * rstd;
  po[i] = r;
}

// f32 fallback tail
__global__ __launch_bounds__(256) void k_encstats32(const float* __restrict__ out, double* __restrict__ dws) {
  __shared__ float red[4][2];
  int s = blockIdx.x >> 2, sub = blockIdx.x & 3, tid = threadIdx.x;
  const float4* p = (const float4*)(out + ((size_t)s << 16));
  float S = 0, SS = 0;
#pragma unroll 4
  for (int it = 0; it < 16; it++) {
    float4 a = p[sub * 256 + tid + it * 1024];
    S += a.x + a.y + a.z + a.w;
    SS += a.x * a.x + a.y * a.y + a.z * a.z + a.w * a.w;
  }
  S = wred64(S); SS = wred64(SS);
  int wave = tid >> 6, lane = tid & 63;
  if (lane == 0) { red[wave][0] = S; red[wave][1] = SS; }
  __syncthreads();
  if (tid < 2) {
    double v = (double)red[0][tid] + red[1][tid] + red[2][tid] + red[3][tid];
    atomicAdd(&dws[EB + (s * 2 + tid) * 4 + sub], v);
  }
}

__global__ __launch_bounds__(256) void k_inorm32(const double* __restrict__ dws, float* __restrict__ out) {
  int s = blockIdx.y;
  double S = 0, SS = 0;
#pragma unroll
  for (int sh = 0; sh < 4; sh++) {
    S  += dws[EB + (s * 2 + 0) * 4 + sh];
    SS += dws[EB + (s * 2 + 1) * 4 + sh];
  }
  double m = S / 65536.0, v = SS / 65536.0 - m * m;
  float rstd = (float)(1.0 / sqrt(v + 1e-5));
  float mf = (float)m;
  float4* p = (float4*)(out + ((size_t)s << 16));
  int i = blockIdx.x * 256 + threadIdx.x;
  float4 a = p[i];
  a.x = (a.x - mf) * rstd;
  a.y = (a.y - mf) * rstd;
  a.z = (a.z - mf) * rstd;
  a.w = (a.w - mf) * rstd;
  p[i] = a;
}

extern "C" void kernel_launch(void* const* d_in, const int* in_sizes, int n_in,
                              void* d_out, int out_size, void* d_ws, size_t ws_size,
                              hipStream_t stream) {
  const float* x     = (const float*)d_in[0];
  const float* w0    = (const float*)d_in[1];
  const float* g0    = (const float*)d_in[2];
  const float* b0    = (const float*)d_in[3];
  const float* wrt   = (const float*)d_in[4];
  const float* grt   = (const float*)d_in[5];
  const float* brt   = (const float*)d_in[6];
  const float* wtt   = (const float*)d_in[7];
  const float* gtt   = (const float*)d_in[8];
  const float* btt   = (const float*)d_in[9];
  const float* wth   = (const float*)d_in[10];
  const float* bth   = (const float*)d_in[11];
  const float* gmin  = (const float*)d_in[12];
  const float* bmin  = (const float*)d_in[13];
  const float* gmax  = (const float*)d_in[14];
  const float* bmax  = (const float*)d_in[15];
  const float* gmean = (const float*)d_in[16];
  const float* bmean = (const float*)d_in[17];
  double* dws = (double*)d_ws;
  unsigned int* pRT = (unsigned int*)((char*)d_ws + 65536);
  unsigned int* pMM = pRT + 12 * NP;
  unsigned short* pENC = (unsigned short*)(pMM + 32 * NP);
  const size_t need16 = 65536 + (size_t)12 * NP * 4 + (size_t)32 * NP * 4 + (size_t)32 * NP * 2;
  const bool big = ws_size >= need16;
  float* out = (float*)d_out;

  hipMemsetAsync(d_ws, 0, DWN * sizeof(double), stream);
  hipLaunchKernelGGL(k_xstats, dim3(768), dim3(256), 0, stream, x, dws);
  hipLaunchKernelGGL(k_passB, dim3(1024), dim3(256), 0, stream, x, wrt, wtt, w0, g0, b0, pRT, pMM, dws);
  hipLaunchKernelGGL(k_stats, dim3(1024), dim3(256), 0, stream, pMM, dws);
  if (big) {
    hipLaunchKernelGGL((k_passC<true>), dim3(1024), dim3(256), 0, stream, pRT, pMM, wth, bth,
                       grt, brt, gtt, btt, gmin, bmin, gmax, bmax, gmean, bmean, dws, out, pENC);
    hipLaunchKernelGGL(k_encstats16, dim3(512), dim3(256), 0, stream, pENC, dws);
    hipLaunchKernelGGL(k_inorm16, dim3(64, 128), dim3(256), 0, stream, dws, pENC, out);
  } else {
    hipLaunchKernelGGL((k_passC<false>), dim3(1024), dim3(256), 0, stream, pRT, pMM, wth, bth,
                       grt, brt, gtt, btt, gmin, bmin, gmax, bmax, gmean, bmean, dws, out, pENC);
    hipLaunchKernelGGL(k_encstats32, dim3(512), dim3(256), 0, stream, out, dws);
    hipLaunchKernelGGL(k_inorm32, dim3(64, 128), dim3(256), 0, stream, dws, out);
  }
}

// Round 13
// 103.227 us; speedup vs baseline: 1.5976x; 1.0001x over previous
//
#include <hip/hip_runtime.h>
#include <math.h>

// Problem constants (B,C,T,H,W)=(4,3,12,256,256), CH0=32
#define HW_    65536
#define THW_   786432      // T*H*W
#define NP     262144      // B*H*W pixels
#define N1_    3145728.0   // B*T*H*W
#define N3_    262144.0    // B*H*W

// dws shard layout (doubles) — shards CACHE-LINE SEPARATED where writer count is high:
//   XB: x-stats, 9 q; 32 shards, slot = XB + s*16 + i         [0,512)
//   SB: h min/max stats, 128 q x 8 dense shards, q*8+s        [512,1536)
//   RB: rt/tt stats, 4 q; 32 shards, slot = RB + s*8 + j      [1536,1792)
//   EB: enc-stats, 256 q x 4 dense shards, q*4+s              [1792,2816)
#define XB 0
#define SB 512
#define RB 1536
#define EB 1792
#define DWN 2816

__device__ __constant__ float PW_[5] = {-0.33647654f, 0.20279402f, 0.77575913f, 0.20279402f, -0.33647654f};
__device__ __constant__ float RW_[5] = {-0.2f, -0.1f, 0.0f, 0.1f, 0.2f};

typedef __fp16 fp16x2 __attribute__((ext_vector_type(2)));
union H2U { fp16x2 h; unsigned int u; };
__device__ __forceinline__ unsigned int packh(float a, float b) {
  H2U x; x.h = __builtin_amdgcn_cvt_pkrtz(a, b); return x.u;
}
__device__ __forceinline__ float2 unpackh(unsigned int v) {
  H2U x; x.u = v; return make_float2((float)x.h.x, (float)x.h.y);
}
__device__ __forceinline__ unsigned short pack1h(float a) {
  return (unsigned short)(packh(a, 0.f) & 0xffffu);
}

__device__ __forceinline__ float wred64(float v) {
#pragma unroll
  for (int m = 32; m > 0; m >>= 1) v += __shfl_xor(v, m, 64);
  return v;
}

__device__ __forceinline__ float fsilu(float y) {
  float e = __expf(-y);
  return y * __builtin_amdgcn_rcpf(1.0f + e);
}

// x statistics: 1536 blocks, 6 float4 loads/thread (2 b's each), line-sep shards.
__global__ __launch_bounds__(256) void k_xstats(const float* __restrict__ x, double* __restrict__ dws) {
  const int bb = blockIdx.x & 1;                       // b-pair select
  const int v = (blockIdx.x >> 1) * 256 + threadIdx.x; // float4 index [0,196608)
  const float4* x4 = (const float4*)x;
  float s0 = 0, s1 = 0, s2 = 0, p00 = 0, p01 = 0, p02 = 0, p11 = 0, p12 = 0, p22 = 0;
#pragma unroll
  for (int bi = 0; bi < 2; bi++) {
    int b = bb * 2 + bi;
    float4 a0 = x4[(size_t)(b * 3 + 0) * 196608 + v];
    float4 a1 = x4[(size_t)(b * 3 + 1) * 196608 + v];
    float4 a2 = x4[(size_t)(b * 3 + 2) * 196608 + v];
    s0 += a0.x + a0.y + a0.z + a0.w;
    s1 += a1.x + a1.y + a1.z + a1.w;
    s2 += a2.x + a2.y + a2.z + a2.w;
    p00 += a0.x * a0.x + a0.y * a0.y + a0.z * a0.z + a0.w * a0.w;
    p11 += a1.x * a1.x + a1.y * a1.y + a1.z * a1.z + a1.w * a1.w;
    p22 += a2.x * a2.x + a2.y * a2.y + a2.z * a2.z + a2.w * a2.w;
    p01 += a0.x * a1.x + a0.y * a1.y + a0.z * a1.z + a0.w * a1.w;
    p02 += a0.x * a2.x + a0.y * a2.y + a0.z * a2.z + a0.w * a2.w;
    p12 += a1.x * a2.x + a1.y * a2.y + a1.z * a2.z + a1.w * a2.w;
  }
  float vals[9] = {s0, s1, s2, p00, p01, p02, p11, p12, p22};
  __shared__ float red[4][9];
  int wave = threadIdx.x >> 6, lane = threadIdx.x & 63;
#pragma unroll
  for (int q = 0; q < 9; q++) vals[q] = wred64(vals[q]);
  if (lane == 0) {
#pragma unroll
    for (int q = 0; q < 9; q++) red[wave][q] = vals[q];
  }
  __syncthreads();
  if (threadIdx.x < 9) {
    double t = (double)red[0][threadIdx.x] + red[1][threadIdx.x] + red[2][threadIdx.x] + red[3][threadIdx.x];
    atomicAdd(&dws[XB + (blockIdx.x & 31) * 16 + threadIdx.x], t);
  }
}

// passB: wave-level 2-way o-split. Block=256 thr over 128 pixels.
// Waves 0-1 (g0): o[0,16) + tconv + pRT + rt/tt stats. Waves 2-3 (g1): o[16,32).
// Every wave spans 64 consecutive pixels -> full coalescing. Grid 2048 -> 32 waves/CU.
__global__ __launch_bounds__(256) void k_passB(const float* __restrict__ x, const float* __restrict__ wrt,
                                               const float* __restrict__ wtt, const float* __restrict__ w0,
                                               const float* __restrict__ g0, const float* __restrict__ b0,
                                               unsigned int* __restrict__ pRT, unsigned int* __restrict__ pMM,
                                               double* __restrict__ dws) {
  const int tid = threadIdx.x;
  const int g = tid >> 7;           // wave-uniform group
  const int pl = tid & 127;
  const int pix = blockIdx.x * 128 + pl;
  const int b = pix >> 16, hw = pix & 65535;
  __shared__ float lrt[128][13];
  __shared__ float red[2][4];
  __shared__ float cfa0[32], cfa1[32], cfa2[32], cfb[32];

  if (tid < 32) {
    int o = tid;
    double q[9];
#pragma unroll
    for (int i = 0; i < 9; i++) {
      double t = 0;
#pragma unroll
      for (int s = 0; s < 32; s++) t += dws[XB + s * 16 + i];
      q[i] = t / N1_;
    }
    double c0 = w0[o * 3 + 0], c1 = w0[o * 3 + 1], c2 = w0[o * 3 + 2];
    double Ey = c0 * q[0] + c1 * q[1] + c2 * q[2];
    double Ey2 = c0 * c0 * q[3] + c1 * c1 * q[6] + c2 * c2 * q[8] +
                 2.0 * (c0 * c1 * q[4] + c0 * c2 * q[5] + c1 * c2 * q[7]);
    double var = Ey2 - Ey * Ey;
    double alpha = (double)g0[o] / sqrt(var + 1e-5);
    cfa0[o] = (float)(alpha * c0);
    cfa1[o] = (float)(alpha * c1);
    cfa2[o] = (float)(alpha * c2);
    cfb[o]  = (float)((double)b0[o] - Ey * alpha);
  }
  __syncthreads();

  const float* xp = x + (size_t)b * 3 * THW_ + hw;
  float xv[3][12];
#pragma unroll
  for (int c = 0; c < 3; c++)
#pragma unroll
    for (int t = 0; t < 12; t++) xv[c][t] = xp[(size_t)(c * 12 + t) * HW_];

  float ttp[12];
  if (g == 0) {
    float wt[3] = {wtt[0], wtt[1], wtt[2]};
#pragma unroll
    for (int t = 0; t < 12; t++) {
      float acc = 0.f;
#pragma unroll
      for (int c = 0; c < 3; c++) {
        float pk = 0.f, sl = 0.f;
#pragma unroll
        for (int j = 0; j < 5; j++) {
          int tj = t - 2 + j;
          if (tj >= 0 && tj < 12) {
            pk = fmaf(PW_[j], xv[c][tj], pk);
            sl = fmaf(RW_[j], xv[c][tj], sl);
          }
        }
        acc = fmaf(wt[c], pk + fabsf(sl), acc);
      }
      ttp[t] = acc;
    }
  }

  float rt_t[12];
#pragma unroll
  for (int t = 0; t < 12; t++) rt_t[t] = 0.f;
  const int ob = g * 16;
#pragma unroll
  for (int oo = 0; oo < 16; oo++) {
    int o = ob + oo;
    float a0 = cfa0[o], a1 = cfa1[o], a2 = cfa2[o];
    float bet = cfb[o], wo = wrt[o];
    float mn = 3.4e38f, mx = -3.4e38f;
#pragma unroll
    for (int t = 0; t < 12; t++) {
      float y = fmaf(a0, xv[0][t], fmaf(a1, xv[1][t], fmaf(a2, xv[2][t], bet)));
      float h = fsilu(y);
      mn = fminf(mn, h);
      mx = fmaxf(mx, h);
      rt_t[t] = fmaf(wo, h, rt_t[t]);
    }
    pMM[o * NP + pix] = packh(mn, mx);
  }

  if (g == 1) {
#pragma unroll
    for (int t = 0; t < 12; t++) lrt[pl][t] = rt_t[t];
  }
  __syncthreads();
  if (g == 0) {
#pragma unroll
    for (int t = 0; t < 12; t++) rt_t[t] += lrt[pl][t];
#pragma unroll
    for (int t = 0; t < 12; t++) pRT[t * NP + pix] = packh(rt_t[t], ttp[t]);
    // rt/tt scalar stats over full rt (waves 0-1 only)
    float srt = 0.f, ssrt = 0.f, stt = 0.f, sstt = 0.f;
#pragma unroll
    for (int t = 0; t < 12; t++) {
      srt += rt_t[t];  ssrt = fmaf(rt_t[t], rt_t[t], ssrt);
      stt += ttp[t];   sstt = fmaf(ttp[t], ttp[t], sstt);
    }
    srt = wred64(srt); ssrt = wred64(ssrt); stt = wred64(stt); sstt = wred64(sstt);
    int wave = tid >> 6, lane = tid & 63;
    if (lane == 0) { red[wave][0] = srt; red[wave][1] = ssrt; red[wave][2] = stt; red[wave][3] = sstt; }
  }
  __syncthreads();
  if (tid < 4) {
    double v = (double)red[0][tid] + red[1][tid];
    atomicAdd(&dws[RB + (blockIdx.x & 31) * 8 + tid], v);
  }
}

// min/max stats over pMM: 1024 blocks (32 per o); pMM is L2/L3-resident.
__global__ __launch_bounds__(256) void k_stats(const unsigned int* __restrict__ pMM,
                                               double* __restrict__ dws) {
  __shared__ float red[4][4];
  int o = blockIdx.x >> 5, sub = blockIdx.x & 31, tid = threadIdx.x;
  const uint4* p = (const uint4*)(pMM + (size_t)o * NP);   // 65536 uint4 per o
  int base = sub * 256 + tid;
  float s0 = 0, s1 = 0, s2 = 0, s3 = 0;
#pragma unroll
  for (int it = 0; it < 8; it++) {
    uint4 v = p[base + it * 8192];
    float2 a = unpackh(v.x), b = unpackh(v.y), c = unpackh(v.z), d = unpackh(v.w);
    s0 += a.x + b.x + c.x + d.x;
    s1 += a.x * a.x + b.x * b.x + c.x * c.x + d.x * d.x;
    s2 += a.y + b.y + c.y + d.y;
    s3 += a.y * a.y + b.y * b.y + c.y * c.y + d.y * d.y;
  }
  s0 = wred64(s0); s1 = wred64(s1); s2 = wred64(s2); s3 = wred64(s3);
  int wave = tid >> 6, lane = tid & 63;
  if (lane == 0) { red[wave][0] = s0; red[wave][1] = s1; red[wave][2] = s2; red[wave][3] = s3; }
  __syncthreads();
  if (tid < 4) {
    double v = (double)red[0][tid] + red[1][tid] + red[2][tid] + red[3][tid];
    atomicAdd(&dws[SB + (o * 4 + tid) * 8 + (blockIdx.x & 7)], v);
  }
}

// passC: finB prologue + enc assembly; fp16 enc to penc (or f32 fallback).
template<bool FP16OUT>
__global__ __launch_bounds__(256) void k_passC(const unsigned int* __restrict__ pRT,
                                               const unsigned int* __restrict__ pMM,
                                               const float* __restrict__ wth, const float* __restrict__ bth,
                                               const float* __restrict__ grt, const float* __restrict__ brt,
                                               const float* __restrict__ gtt, const float* __restrict__ btt,
                                               const float* __restrict__ gmin, const float* __restrict__ bmin,
                                               const float* __restrict__ gmax, const float* __restrict__ bmax,
                                               const float* __restrict__ gmean, const float* __restrict__ bmean,
                                               const double* __restrict__ dws, float* __restrict__ out,
                                               unsigned short* __restrict__ penc) {
  const int tid = threadIdx.x;
  const int pix = blockIdx.x * 256 + tid;
  const int b = pix >> 16, hw = pix & 65535;
  __shared__ float camn[32], cbmn[32], camx[32], cbmx[32], came[32], cbme[32];
  __shared__ float c4[4];

  if (tid < 32) {
    double q[4];
#pragma unroll
    for (int i = 0; i < 4; i++) {
      double t = 0;
#pragma unroll
      for (int s = 0; s < 8; s++) t += dws[SB + (tid * 4 + i) * 8 + s];
      q[i] = t / N3_;
    }
    double m = q[0], v = q[1] - m * m;
    double a = (double)gmin[tid] / sqrt(v + 1e-5);
    camn[tid] = (float)a; cbmn[tid] = (float)((double)bmin[tid] - m * a);
    double mm = q[2], vv = q[3] - mm * mm;
    a = (double)gmax[tid] / sqrt(vv + 1e-5);
    camx[tid] = (float)a; cbmx[tid] = (float)((double)bmax[tid] - mm * a);
    a = (double)gmean[tid] / sqrt(vv + 1e-5);
    came[tid] = (float)a; cbme[tid] = (float)((double)bmean[tid] - mm * a);
  }
  if (tid == 32) {
    double q[4];
#pragma unroll
    for (int i = 0; i < 4; i++) {
      double t = 0;
#pragma unroll
      for (int s = 0; s < 32; s++) t += dws[RB + s * 8 + i];
      q[i] = t / N1_;
    }
    double m = q[0], v = q[1] - m * m;
    double a = (double)grt[0] / sqrt(v + 1e-5);
    c4[0] = (float)a; c4[1] = (float)((double)brt[0] - m * a);
    m = q[2]; v = q[3] - m * m;
    a = (double)gtt[0] / sqrt(v + 1e-5);
    c4[2] = (float)a; c4[3] = (float)((double)btt[0] - m * a);
  }
  __syncthreads();

  float art = c4[0], brt_ = c4[1], att = c4[2], btt_ = c4[3];
  float rtt[12];
#pragma unroll
  for (int t = 0; t < 12; t++) {
    float2 v = unpackh(pRT[t * NP + pix]);
    rtt[t] = fsilu(fmaf(art, v.x, brt_)) + fsilu(fmaf(att, v.y, btt_));
  }
  float* po = out + (size_t)b * 32 * HW_ + hw;
  unsigned short* pe = penc + ((size_t)(b * 32) << 16) + hw;
#pragma unroll
  for (int o = 0; o < 32; o++) {
    float2 mm = unpackh(pMM[o * NP + pix]);
    float tl = bth[o];
#pragma unroll
    for (int t = 0; t < 12; t++) tl = fmaf(wth[o * 12 + t], rtt[t], tl);
    float e = tl + fsilu(fmaf(camn[o], mm.x, cbmn[o]))
                 + fsilu(fmaf(camx[o], mm.y, cbmx[o]))
                 + fsilu(fmaf(came[o], mm.y, cbme[o]));
    if (FP16OUT) pe[(size_t)o << 16] = pack1h(e);
    else         po[(size_t)o * HW_] = e;
  }
}

// enc stats, fp16 source (4 blocks per slice)
__global__ __launch_bounds__(256) void k_encstats16(const unsigned short* __restrict__ penc,
                                                    double* __restrict__ dws) {
  __shared__ float red[4][2];
  int s = blockIdx.x >> 2, sub = blockIdx.x & 3, tid = threadIdx.x;
  const uint4* p = (const uint4*)(penc + ((size_t)s << 16));   // 8192 uint4 per slice
  float S = 0, SS = 0;
#pragma unroll
  for (int it = 0; it < 8; it++) {
    uint4 v = p[sub * 2048 + tid + it * 256];
    float2 a = unpackh(v.x), b = unpackh(v.y), c = unpackh(v.z), d = unpackh(v.w);
    S += a.x + a.y + b.x + b.y + c.x + c.y + d.x + d.y;
    SS += a.x * a.x + a.y * a.y + b.x * b.x + b.y * b.y +
          c.x * c.x + c.y * c.y + d.x * d.x + d.y * d.y;
  }
  S = wred64(S); SS = wred64(SS);
  int wave = tid >> 6, lane = tid & 63;
  if (lane == 0) { red[wave][0] = S; red[wave][1] = SS; }
  __syncthreads();
  if (tid < 2) {
    double v = (double)red[0][tid] + red[1][tid] + red[2][tid] + red[3][tid];
    atomicAdd(&dws[EB + (s * 2 + tid) * 4 + sub], v);
  }
}

__global__ __launch_bounds__(256) void k_inorm16(const double* __restrict__ dws,
                                                 const unsigned short* __restrict__ penc,
                                                 float* __restrict__ out) {
  int s = blockIdx.y;
  double S = 0, SS = 0;
#pragma unroll
  for (int sh = 0; sh < 4; sh++) {
    S  += dws[EB + (s * 2 + 0) * 4 + sh];
    SS += dws[EB + (s * 2 + 1) * 4 + sh];
  }
  double m = S / 65536.0, v = SS / 65536.0 - m * m;
  float rstd = (float)(1.0 / sqrt(v + 1e-5));
  float mf = (float)m;
  const uint2* p = (const uint2*)(penc + ((size_t)s << 16));   // 16384 uint2
  float4* po = (float4*)(out + ((size_t)s << 16));
  int i = blockIdx.x * 256 + threadIdx.x;
  uint2 u = p[i];
  float2 a = unpackh(u.x), b = unpackh(u.y);
  float4 r;
  r.x = (a.x - mf) * rstd;
  r.y = (a.y - mf) * rstd;
  r.z = (b.x - mf) * rstd;
  r.w = (b.y - mf) * rstd;
  po[i] = r;
}

// f32 fallback tail
__global__ __launch_bounds__(256) void k_encstats32(const float* __restrict__ out, double* __restrict__ dws) {
  __shared__ float red[4][2];
  int s = blockIdx.x >> 2, sub = blockIdx.x & 3, tid = threadIdx.x;
  const float4* p = (const float4*)(out + ((size_t)s << 16));
  float S = 0, SS = 0;
#pragma unroll 4
  for (int it = 0; it < 16; it++) {
    float4 a = p[sub * 256 + tid + it * 1024];
    S += a.x + a.y + a.z + a.w;
    SS += a.x * a.x + a.y * a.y + a.z * a.z + a.w * a.w;
  }
  S = wred64(S); SS = wred64(SS);
  int wave = tid >> 6, lane = tid & 63;
  if (lane == 0) { red[wave][0] = S; red[wave][1] = SS; }
  __syncthreads();
  if (tid < 2) {
    double v = (double)red[0][tid] + red[1][tid] + red[2][tid] + red[3][tid];
    atomicAdd(&dws[EB + (s * 2 + tid) * 4 + sub], v);
  }
}

__global__ __launch_bounds__(256) void k_inorm32(const double* __restrict__ dws, float* __restrict__ out) {
  int s = blockIdx.y;
  double S = 0, SS = 0;
#pragma unroll
  for (int sh = 0; sh < 4; sh++) {
    S  += dws[EB + (s * 2 + 0) * 4 + sh];
    SS += dws[EB + (s * 2 + 1) * 4 + sh];
  }
  double m = S / 65536.0, v = SS / 65536.0 - m * m;
  float rstd = (float)(1.0 / sqrt(v + 1e-5));
  float mf = (float)m;
  float4* p = (float4*)(out + ((size_t)s << 16));
  int i = blockIdx.x * 256 + threadIdx.x;
  float4 a = p[i];
  a.x = (a.x - mf) * rstd;
  a.y = (a.y - mf) * rstd;
  a.z = (a.z - mf) * rstd;
  a.w = (a.w - mf) * rstd;
  p[i] = a;
}

extern "C" void kernel_launch(void* const* d_in, const int* in_sizes, int n_in,
                              void* d_out, int out_size, void* d_ws, size_t ws_size,
                              hipStream_t stream) {
  const float* x     = (const float*)d_in[0];
  const float* w0    = (const float*)d_in[1];
  const float* g0    = (const float*)d_in[2];
  const float* b0    = (const float*)d_in[3];
  const float* wrt   = (const float*)d_in[4];
  const float* grt   = (const float*)d_in[5];
  const float* brt   = (const float*)d_in[6];
  const float* wtt   = (const float*)d_in[7];
  const float* gtt   = (const float*)d_in[8];
  const float* btt   = (const float*)d_in[9];
  const float* wth   = (const float*)d_in[10];
  const float* bth   = (const float*)d_in[11];
  const float* gmin  = (const float*)d_in[12];
  const float* bmin  = (const float*)d_in[13];
  const float* gmax  = (const float*)d_in[14];
  const float* bmax  = (const float*)d_in[15];
  const float* gmean = (const float*)d_in[16];
  const float* bmean = (const float*)d_in[17];
  double* dws = (double*)d_ws;
  unsigned int* pRT = (unsigned int*)((char*)d_ws + 65536);
  unsigned int* pMM = pRT + 12 * NP;
  unsigned short* pENC = (unsigned short*)(pMM + 32 * NP);
  const size_t need16 = 65536 + (size_t)12 * NP * 4 + (size_t)32 * NP * 4 + (size_t)32 * NP * 2;
  const bool big = ws_size >= need16;
  float* out = (float*)d_out;

  hipMemsetAsync(d_ws, 0, DWN * sizeof(double), stream);
  hipLaunchKernelGGL(k_xstats, dim3(1536), dim3(256), 0, stream, x, dws);
  hipLaunchKernelGGL(k_passB, dim3(2048), dim3(256), 0, stream, x, wrt, wtt, w0, g0, b0, pRT, pMM, dws);
  hipLaunchKernelGGL(k_stats, dim3(1024), dim3(256), 0, stream, pMM, dws);
  if (big) {
    hipLaunchKernelGGL((k_passC<true>), dim3(1024), dim3(256), 0, stream, pRT, pMM, wth, bth,
                       grt, brt, gtt, btt, gmin, bmin, gmax, bmax, gmean, bmean, dws, out, pENC);
    hipLaunchKernelGGL(k_encstats16, dim3(512), dim3(256), 0, stream, pENC, dws);
    hipLaunchKernelGGL(k_inorm16, dim3(64, 128), dim3(256), 0, stream, dws, pENC, out);
  } else {
    hipLaunchKernelGGL((k_passC<false>), dim3(1024), dim3(256), 0, stream, pRT, pMM, wth, bth,
                       grt, brt, gtt, btt, gmin, bmin, gmax, bmax, gmean, bmean, dws, out, pENC);
    hipLaunchKernelGGL(k_encstats32, dim3(512), dim3(256), 0, stream, out, dws);
    hipLaunchKernelGGL(k_inorm32, dim3(64, 128), dim3(256), 0, stream, dws, out);
  }
}